// Round 5
// baseline (363.472 us; speedup 1.0000x reference)
//
#include <hip/hip_runtime.h>
#include <cstdint>
#include <cstddef>

#define DIM   512
#define QKD   128
#define HID   1024
#define SEQ   4096
#define BAT   4
#define TOK   (BAT*SEQ)

typedef float f32x4 __attribute__((ext_vector_type(4)));
typedef int   i32x4 __attribute__((ext_vector_type(4)));
typedef int   i32x8 __attribute__((ext_vector_type(8)));

__device__ __forceinline__ unsigned short f2b(float f) {
    unsigned u = __builtin_bit_cast(unsigned, f);
    u += 0x7FFFu + ((u >> 16) & 1u);
    return (unsigned short)(u >> 16);
}
__device__ __forceinline__ float silu_f(float x) { return x / (1.f + __expf(-x)); }

__device__ __forceinline__ unsigned char f2e4(float f) {
    int v = __builtin_amdgcn_cvt_pk_fp8_f32(f, 0.f, 0, false);
    return (unsigned char)(v & 0xff);
}
__device__ __forceinline__ unsigned f2e4x4(float a, float b, float c, float d) {
    int w = __builtin_amdgcn_cvt_pk_fp8_f32(a, b, 0, false);
    w = __builtin_amdgcn_cvt_pk_fp8_f32(c, d, w, true);
    return (unsigned)w;
}
__device__ __forceinline__ float e42f(unsigned char b) {
    return __builtin_amdgcn_cvt_f32_fp8((int)b, 0);
}

__device__ __forceinline__ void load16_lds(const void* gp, void* lp) {
    __builtin_amdgcn_global_load_lds(
        (const __attribute__((address_space(1))) unsigned int*)gp,
        (__attribute__((address_space(3))) unsigned int*)lp,
        16, 0, 0);
}

// ---------------- LayerNorm: fp32 x -> fp8 normed ----------------
__global__ __launch_bounds__(256) void ln_kernel(
    const float* __restrict__ x, const float* __restrict__ sc,
    const float* __restrict__ bi, unsigned char* __restrict__ out)
{
    const int lane = threadIdx.x & 63, wid = threadIdx.x >> 6;
    const int row  = blockIdx.x * 4 + wid;
    const float4* xr = (const float4*)(x + (size_t)row * DIM);
    float4 a = xr[lane], b = xr[64 + lane];
    float s = a.x + a.y + a.z + a.w + b.x + b.y + b.z + b.w;
    float q = a.x*a.x + a.y*a.y + a.z*a.z + a.w*a.w
            + b.x*b.x + b.y*b.y + b.z*b.z + b.w*b.w;
#pragma unroll
    for (int m = 1; m < 64; m <<= 1) { s += __shfl_xor(s, m); q += __shfl_xor(q, m); }
    const float mean = s * (1.f / DIM);
    const float var  = q * (1.f / DIM) - mean * mean;
    const float rs   = rsqrtf(var + 1e-5f);
    float4 s0 = ((const float4*)sc)[lane], s1 = ((const float4*)sc)[64 + lane];
    float4 b0 = ((const float4*)bi)[lane], b1 = ((const float4*)bi)[64 + lane];
    unsigned wlo = f2e4x4((a.x - mean) * rs * s0.x + b0.x,
                          (a.y - mean) * rs * s0.y + b0.y,
                          (a.z - mean) * rs * s0.z + b0.z,
                          (a.w - mean) * rs * s0.w + b0.w);
    unsigned whi = f2e4x4((b.x - mean) * rs * s1.x + b1.x,
                          (b.y - mean) * rs * s1.y + b1.y,
                          (b.z - mean) * rs * s1.z + b1.z,
                          (b.w - mean) * rs * s1.w + b1.w);
    unsigned char* orow = out + (size_t)row * DIM;
    *(unsigned*)(orow + 4 * lane)       = wlo;
    *(unsigned*)(orow + 256 + 4 * lane) = whi;
}

// ---------------- transpose-cast fp32 (RxC) -> fp8 (CxR), x16 ----------------
__global__ __launch_bounds__(256) void tcast_f2e4_kernel(
    const float* __restrict__ in, unsigned char* __restrict__ out, int R, int C)
{
    __shared__ float t[32][33];
    const int tx = threadIdx.x & 31, ty = threadIdx.x >> 5;
    const int c0 = blockIdx.x * 32, r0 = blockIdx.y * 32;
#pragma unroll
    for (int i = 0; i < 4; ++i)
        t[ty + i * 8][tx] = in[(size_t)(r0 + ty + i * 8) * C + c0 + tx];
    __syncthreads();
#pragma unroll
    for (int i = 0; i < 4; ++i)
        out[(size_t)(c0 + ty + i * 8) * R + r0 + tx] = f2e4(t[tx][ty + i * 8] * 16.f);
}

// ---------------- fallback: out = x ----------------
__global__ __launch_bounds__(256) void copy_kernel(
    const float* __restrict__ in, float* __restrict__ out, int n4)
{
    int i = blockIdx.x * 256 + threadIdx.x;
    int stride = gridDim.x * 256;
    for (; i < n4; i += stride)
        ((float4*)out)[i] = ((const float4*)in)[i];
}

// -------- MX-fp8 MFMA GEMM: C = A(MxK) * B(NxK)^T, 128x128 tile --------------
// BK bytes of K staged per iter (128 or 256). NX = gridDim.x (compile-time) for
// the XCD-locality swizzle: same-row blocks get ids == const (mod 8) -> same XCD.
// EPI 0: hidden+qk fused (N=2176): v->vT fp8 T'posed | gate fp8 | q/k fp8 (x64)
// EPI 1: sim  — A8 = (relu(acc)/16)^2 = 2^40 relu(sim)^2 -> fp8
// EPI 2: av   — vg8 = acc * 2^-12 * gate -> fp8 (= 2^28 * V*gate)
// EPI 3: out  — fo = acc * 2^-32 + b_out + x  (fp32)
template<int EPI, int BK, int NX>
__global__ __launch_bounds__(256) void gemm8(
    const unsigned char* __restrict__ A, const unsigned char* __restrict__ B,
    int K, long strAz, long strBz, long strOz,
    const float* __restrict__ f0, const float* __restrict__ f1,
    const float* __restrict__ f2, const float* __restrict__ f3,
    const float* __restrict__ f4, const float* __restrict__ f5,
    unsigned char* __restrict__ gate,
    unsigned char* __restrict__ o0, unsigned char* __restrict__ o1,
    unsigned char* __restrict__ o2,
    float* __restrict__ fo, float scale)
{
    constexpr int TPR = BK / 16;          // threads per staged row
    constexpr int RPI = 256 / TPR;        // rows per staging issue
    constexpr int NIS = 128 / RPI;        // issues per matrix tile
    __shared__ unsigned char lds[2 * 128 * BK];   // A: [0,128*BK), B after

    const int tid = threadIdx.x;
    // XCD-locality swizzle (dispatch id -> tile coords)
    const int d  = blockIdx.x + NX * blockIdx.y;
    const int qd = d >> 3;
    const int m0 = ((d & 7) + 8 * (qd / NX)) * 128;
    const int n0 = (qd % NX) * 128;
    const int z  = blockIdx.z;
    A += (size_t)z * strAz;  B += (size_t)z * strBz;
    const int lane = tid & 63, wid = tid >> 6;
    const int wm   = (wid & 1) * 64, wn = (wid >> 1) * 64;
    const int l15  = lane & 15, quad = lane >> 4;

    f32x4 acc[4][4] = {};

    const int srow = tid / TPR, sseg = tid % TPR;
    const unsigned char* gA = A + (size_t)(m0 + srow) * K + sseg * 16;
    const unsigned char* gB = B + (size_t)(n0 + srow) * K + sseg * 16;
    unsigned char* lA = lds + (size_t)tid * 16;
    unsigned char* lB = lds + 128 * BK + (size_t)tid * 16;

    for (int kt = 0; kt < K; kt += BK) {
#pragma unroll
        for (int i = 0; i < NIS; ++i)
            load16_lds(gA + (size_t)i * RPI * K + kt, lA + i * 4096);
#pragma unroll
        for (int i = 0; i < NIS; ++i)
            load16_lds(gB + (size_t)i * RPI * K + kt, lB + i * 4096);
        __syncthreads();
#pragma unroll
        for (int kk = 0; kk < BK; kk += 128) {
            i32x4 alo[4], ahi[4], blo[4], bhi[4];
#pragma unroll
            for (int mi = 0; mi < 4; ++mi) {
                const unsigned char* p = lds + (size_t)(wm + mi * 16 + l15) * BK + kk + quad * 32;
                alo[mi] = *(const i32x4*)p; ahi[mi] = *(const i32x4*)(p + 16);
            }
#pragma unroll
            for (int ni = 0; ni < 4; ++ni) {
                const unsigned char* p = lds + 128 * BK + (size_t)(wn + ni * 16 + l15) * BK + kk + quad * 32;
                blo[ni] = *(const i32x4*)p; bhi[ni] = *(const i32x4*)(p + 16);
            }
#pragma unroll
            for (int mi = 0; mi < 4; ++mi) {
                i32x8 af = __builtin_shufflevector(alo[mi], ahi[mi], 0,1,2,3,4,5,6,7);
#pragma unroll
                for (int ni = 0; ni < 4; ++ni) {
                    i32x8 bf = __builtin_shufflevector(blo[ni], bhi[ni], 0,1,2,3,4,5,6,7);
                    acc[mi][ni] = __builtin_amdgcn_mfma_scale_f32_16x16x128_f8f6f4(
                        af, bf, acc[mi][ni], 0, 0,
                        0, 0x7F7F7F7F, 0, 0x7F7F7F7F);   // unit scales
                }
            }
        }
        __syncthreads();
    }

    // C/D layout: col = lane&15, row = quad*4 + reg
#pragma unroll
    for (int mi = 0; mi < 4; ++mi)
#pragma unroll
    for (int ni = 0; ni < 4; ++ni) {
        const int grow0 = m0 + wm + mi * 16 + quad * 4;
        const int gcol  = n0 + wn + ni * 16 + l15;
        if constexpr (EPI == 0) {
            if (gcol < HID) {
                const int b = grow0 >> 12, rloc = grow0 & (SEQ - 1);
                unsigned w = f2e4x4(silu_f(acc[mi][ni][0] * 0.0625f + f0[gcol]),
                                    silu_f(acc[mi][ni][1] * 0.0625f + f0[gcol]),
                                    silu_f(acc[mi][ni][2] * 0.0625f + f0[gcol]),
                                    silu_f(acc[mi][ni][3] * 0.0625f + f0[gcol]));
                *(unsigned*)(o0 + (size_t)b * HID * SEQ + (size_t)gcol * SEQ + rloc) = w;
            } else if (gcol < 2048) {
#pragma unroll
                for (int r = 0; r < 4; ++r)
                    gate[(size_t)(grow0 + r) * HID + (gcol - HID)] =
                        f2e4(silu_f(acc[mi][ni][r] * 0.0625f + f0[gcol]));
            } else {
                const int c = gcol - 2048;
#pragma unroll
                for (int r = 0; r < 4; ++r) {
                    float zf = silu_f(acc[mi][ni][r] * 0.0625f + f1[c]);
                    o1[(size_t)(grow0 + r) * QKD + c] = f2e4((zf * f2[c] + f4[c]) * 64.f);
                    o2[(size_t)(grow0 + r) * QKD + c] = f2e4((zf * f3[c] + f5[c]) * 64.f);
                }
            }
        } else if constexpr (EPI == 1) {
            unsigned char* Ao = o0 + (size_t)z * strOz;
#pragma unroll
            for (int r = 0; r < 4; ++r) {
                float t = fmaxf(acc[mi][ni][r], 0.f) * 0.0625f;
                Ao[(size_t)(grow0 + r) * SEQ + gcol] = f2e4(t * t);
            }
        } else if constexpr (EPI == 2) {
            unsigned char* gz = gate + (size_t)z * strOz;
            unsigned char* vo = o0 + (size_t)z * strOz;
#pragma unroll
            for (int r = 0; r < 4; ++r) {
                float g = e42f(gz[(size_t)(grow0 + r) * HID + gcol]);
                vo[(size_t)(grow0 + r) * HID + gcol] = f2e4(acc[mi][ni][r] * scale * g);
            }
        } else {
#pragma unroll
            for (int r = 0; r < 4; ++r)
                fo[(size_t)(grow0 + r) * DIM + gcol] =
                    acc[mi][ni][r] * scale + f0[gcol] + f1[(size_t)(grow0 + r) * DIM + gcol];
        }
    }
}

extern "C" void kernel_launch(void* const* d_in, const int* in_sizes, int n_in,
                              void* d_out, int out_size, void* d_ws, size_t ws_size,
                              hipStream_t stream) {
    const float* x     = (const float*)d_in[0];
    const float* nsc   = (const float*)d_in[1];
    const float* nbi   = (const float*)d_in[2];
    const float* Wh    = (const float*)d_in[3];
    const float* bh    = (const float*)d_in[4];
    const float* Wqk   = (const float*)d_in[5];
    const float* bqk   = (const float*)d_in[6];
    const float* gamma = (const float*)d_in[7];
    const float* beta  = (const float*)d_in[8];
    const float* Wout  = (const float*)d_in[9];
    const float* bout  = (const float*)d_in[10];
    float* out = (float*)d_out;

    uint8_t* ws = (uint8_t*)d_ws;
    size_t off = 0;
    auto alloc = [&](size_t n) { uint8_t* p = ws + off; off += (n + 255) & ~(size_t)255; return p; };
    unsigned char* normed8 = (unsigned char*)alloc((size_t)TOK * DIM);
    unsigned char* Wc8     = (unsigned char*)alloc((size_t)2176 * DIM);   // [WhT;WqkT] x16
    unsigned char* Wout8   = (unsigned char*)alloc((size_t)DIM * HID);    // x16
    unsigned char* vT8     = (unsigned char*)alloc((size_t)BAT * HID * SEQ);
    unsigned char* gbuf    = (unsigned char*)alloc((size_t)TOK * HID);    // gate fp8
    unsigned char* q8      = (unsigned char*)alloc((size_t)TOK * QKD);    // x64
    unsigned char* k8      = (unsigned char*)alloc((size_t)TOK * QKD);    // x64
    unsigned char* Ab8     = (unsigned char*)alloc((size_t)BAT * SEQ * SEQ); // x2^40
    unsigned char* vg8     = (unsigned char*)alloc((size_t)TOK * HID);    // x2^28

    if (ws_size < off) {
        copy_kernel<<<4096, 256, 0, stream>>>(x, out, TOK * DIM / 4);
        return;
    }

    ln_kernel<<<TOK / 4, 256, 0, stream>>>(x, nsc, nbi, normed8);
    tcast_f2e4_kernel<<<dim3(2048 / 32, DIM / 32), 256, 0, stream>>>(Wh, Wc8, DIM, 2048);
    tcast_f2e4_kernel<<<dim3(QKD / 32, DIM / 32), 256, 0, stream>>>(
        Wqk, Wc8 + (size_t)2048 * DIM, DIM, QKD);
    tcast_f2e4_kernel<<<dim3(DIM / 32, HID / 32), 256, 0, stream>>>(Wout, Wout8, HID, DIM);

    // hidden + qk fused: N = 2176, K = 512, BK=256
    gemm8<0, 256, 17><<<dim3(17, TOK / 128), 256, 0, stream>>>(
        normed8, Wc8, DIM, 0, 0, 0,
        bh, bqk, gamma, gamma + QKD, beta, beta + QKD,
        gbuf, vT8, q8, k8, nullptr, 0.f);

    // sim: K = 128 (single slab), z-batched
    gemm8<1, 128, 32><<<dim3(SEQ / 128, SEQ / 128, BAT), 256, 0, stream>>>(
        q8, k8, QKD, (long)SEQ * QKD, (long)SEQ * QKD, (long)SEQ * SEQ,
        nullptr, nullptr, nullptr, nullptr, nullptr, nullptr,
        nullptr, Ab8, nullptr, nullptr, nullptr, 0.f);

    // A@v: K = 4096, BK=256, z-batched; vg8 = acc * 2^-12 * gate
    gemm8<2, 256, 8><<<dim3(HID / 128, SEQ / 128, BAT), 256, 0, stream>>>(
        Ab8, vT8, SEQ, (long)SEQ * SEQ, (long)HID * SEQ, (long)SEQ * HID,
        nullptr, nullptr, nullptr, nullptr, nullptr, nullptr,
        gbuf, vg8, nullptr, nullptr, nullptr, 0x1p-12f);

    // out: K = 1024, BK=256; out = acc * 2^-32 + b_out + x
    gemm8<3, 256, 4><<<dim3(DIM / 128, TOK / 128), 256, 0, stream>>>(
        vg8, Wout8, HID, 0, 0, 0,
        bout, x, nullptr, nullptr, nullptr, nullptr,
        nullptr, nullptr, nullptr, nullptr, out, 0x1p-32f);
}

// Round 6
// 303.753 us; speedup vs baseline: 1.1966x; 1.1966x over previous
//
#include <hip/hip_runtime.h>
#include <cstdint>
#include <cstddef>

#define DIM   512
#define QKD   128
#define HID   1024
#define SEQ   4096
#define BAT   4
#define TOK   (BAT*SEQ)

typedef float f32x4 __attribute__((ext_vector_type(4)));
typedef int   i32x4 __attribute__((ext_vector_type(4)));
typedef int   i32x8 __attribute__((ext_vector_type(8)));

__device__ __forceinline__ float silu_f(float x) { return x / (1.f + __expf(-x)); }

__device__ __forceinline__ unsigned char f2e4(float f) {
    int v = __builtin_amdgcn_cvt_pk_fp8_f32(f, 0.f, 0, false);
    return (unsigned char)(v & 0xff);
}
__device__ __forceinline__ unsigned f2e4x4(float a, float b, float c, float d) {
    int w = __builtin_amdgcn_cvt_pk_fp8_f32(a, b, 0, false);
    w = __builtin_amdgcn_cvt_pk_fp8_f32(c, d, w, true);
    return (unsigned)w;
}
__device__ __forceinline__ float e42f(unsigned char b) {
    return __builtin_amdgcn_cvt_f32_fp8((int)b, 0);
}

__device__ __forceinline__ void load16_lds(const void* gp, void* lp) {
    __builtin_amdgcn_global_load_lds(
        (const __attribute__((address_space(1))) unsigned int*)gp,
        (__attribute__((address_space(3))) unsigned int*)lp,
        16, 0, 0);
}

// ---------------- LayerNorm: fp32 x -> fp8 normed ----------------
__global__ __launch_bounds__(256) void ln_kernel(
    const float* __restrict__ x, const float* __restrict__ sc,
    const float* __restrict__ bi, unsigned char* __restrict__ out)
{
    const int lane = threadIdx.x & 63, wid = threadIdx.x >> 6;
    const int row  = blockIdx.x * 4 + wid;
    const float4* xr = (const float4*)(x + (size_t)row * DIM);
    float4 a = xr[lane], b = xr[64 + lane];
    float s = a.x + a.y + a.z + a.w + b.x + b.y + b.z + b.w;
    float q = a.x*a.x + a.y*a.y + a.z*a.z + a.w*a.w
            + b.x*b.x + b.y*b.y + b.z*b.z + b.w*b.w;
#pragma unroll
    for (int m = 1; m < 64; m <<= 1) { s += __shfl_xor(s, m); q += __shfl_xor(q, m); }
    const float mean = s * (1.f / DIM);
    const float var  = q * (1.f / DIM) - mean * mean;
    const float rs   = rsqrtf(var + 1e-5f);
    float4 s0 = ((const float4*)sc)[lane], s1 = ((const float4*)sc)[64 + lane];
    float4 b0 = ((const float4*)bi)[lane], b1 = ((const float4*)bi)[64 + lane];
    unsigned wlo = f2e4x4((a.x - mean) * rs * s0.x + b0.x,
                          (a.y - mean) * rs * s0.y + b0.y,
                          (a.z - mean) * rs * s0.z + b0.z,
                          (a.w - mean) * rs * s0.w + b0.w);
    unsigned whi = f2e4x4((b.x - mean) * rs * s1.x + b1.x,
                          (b.y - mean) * rs * s1.y + b1.y,
                          (b.z - mean) * rs * s1.z + b1.z,
                          (b.w - mean) * rs * s1.w + b1.w);
    unsigned char* orow = out + (size_t)row * DIM;
    *(unsigned*)(orow + 4 * lane)       = wlo;
    *(unsigned*)(orow + 256 + 4 * lane) = whi;
}

// ---------------- transpose-cast fp32 (RxC) -> fp8 (CxR), x16 ----------------
__global__ __launch_bounds__(256) void tcast_f2e4_kernel(
    const float* __restrict__ in, unsigned char* __restrict__ out, int R, int C)
{
    __shared__ float t[32][33];
    const int tx = threadIdx.x & 31, ty = threadIdx.x >> 5;
    const int c0 = blockIdx.x * 32, r0 = blockIdx.y * 32;
#pragma unroll
    for (int i = 0; i < 4; ++i)
        t[ty + i * 8][tx] = in[(size_t)(r0 + ty + i * 8) * C + c0 + tx];
    __syncthreads();
#pragma unroll
    for (int i = 0; i < 4; ++i)
        out[(size_t)(c0 + ty + i * 8) * R + r0 + tx] = f2e4(t[tx][ty + i * 8] * 16.f);
}

// ---------------- fallback: out = x ----------------
__global__ __launch_bounds__(256) void copy_kernel(
    const float* __restrict__ in, float* __restrict__ out, int n4)
{
    int i = blockIdx.x * 256 + threadIdx.x;
    int stride = gridDim.x * 256;
    for (; i < n4; i += stride)
        ((float4*)out)[i] = ((const float4*)in)[i];
}

// -------- MX-fp8 MFMA GEMM: C = A(MxK) * B(NxK)^T, 128x128 tile, BK=128 ------
// (BK=256 tried R5: 64KB LDS halves blocks/CU, MfmaUtil 26->18 — m132 redux.)
// NX = gridDim.x (compile-time) for the XCD-locality swizzle: same-M-row
// blocks get dispatch ids == const (mod 8) -> same XCD L2 (R5: FETCH 287->106MB).
// EPI 0: hidden+qk fused (N=2176): v->vT fp8 T'posed | gate fp8 | q/k fp8 (x64)
// EPI 1: sim  — A8 = (relu(acc)/16)^2 = 2^40 relu(sim)^2 -> fp8
// EPI 2: av   — vg8 = acc * 2^-12 * gate -> fp8 (= 2^28 * V*gate)
// EPI 3: out  — fo = acc * 2^-32 + b_out + x  (fp32)
template<int EPI, int NX>
__global__ __launch_bounds__(256) void gemm8(
    const unsigned char* __restrict__ A, const unsigned char* __restrict__ B,
    int K, long strAz, long strBz, long strOz,
    const float* __restrict__ f0, const float* __restrict__ f1,
    const float* __restrict__ f2, const float* __restrict__ f3,
    const float* __restrict__ f4, const float* __restrict__ f5,
    unsigned char* __restrict__ gate,
    unsigned char* __restrict__ o0, unsigned char* __restrict__ o1,
    unsigned char* __restrict__ o2,
    float* __restrict__ fo, float scale)
{
    __shared__ unsigned char lds[32768];          // A: [0,16K), B: [16K,32K)
    const int tid = threadIdx.x;
    // XCD-locality swizzle (dispatch id -> tile coords)
    const int d  = blockIdx.x + NX * blockIdx.y;
    const int qd = d >> 3;
    const int m0 = ((d & 7) + 8 * (qd / NX)) * 128;
    const int n0 = (qd % NX) * 128;
    const int z  = blockIdx.z;
    A += (size_t)z * strAz;  B += (size_t)z * strBz;
    const int lane = tid & 63, wid = tid >> 6;
    const int wm   = (wid & 1) * 64, wn = (wid >> 1) * 64;
    const int l15  = lane & 15, quad = lane >> 4;

    f32x4 acc[4][4] = {};

    // staging: 128 rows x 128 B per matrix per iter; 4 issues of 32 rows each
    const int srow = tid >> 3, sseg = tid & 7;
    const unsigned char* gA = A + (size_t)(m0 + srow) * K + sseg * 16;
    const unsigned char* gB = B + (size_t)(n0 + srow) * K + sseg * 16;
    unsigned char* lA = lds + (size_t)tid * 16;
    unsigned char* lB = lds + 16384 + (size_t)tid * 16;

    for (int kt = 0; kt < K; kt += 128) {
#pragma unroll
        for (int i = 0; i < 4; ++i)
            load16_lds(gA + (size_t)i * 32 * K + kt, lA + i * 4096);
#pragma unroll
        for (int i = 0; i < 4; ++i)
            load16_lds(gB + (size_t)i * 32 * K + kt, lB + i * 4096);
        __syncthreads();
        i32x4 alo[4], ahi[4], blo[4], bhi[4];
#pragma unroll
        for (int mi = 0; mi < 4; ++mi) {
            const unsigned char* p = lds + (wm + mi * 16 + l15) * 128 + quad * 32;
            alo[mi] = *(const i32x4*)p; ahi[mi] = *(const i32x4*)(p + 16);
        }
#pragma unroll
        for (int ni = 0; ni < 4; ++ni) {
            const unsigned char* p = lds + 16384 + (wn + ni * 16 + l15) * 128 + quad * 32;
            blo[ni] = *(const i32x4*)p; bhi[ni] = *(const i32x4*)(p + 16);
        }
#pragma unroll
        for (int mi = 0; mi < 4; ++mi) {
            i32x8 af = __builtin_shufflevector(alo[mi], ahi[mi], 0,1,2,3,4,5,6,7);
#pragma unroll
            for (int ni = 0; ni < 4; ++ni) {
                i32x8 bf = __builtin_shufflevector(blo[ni], bhi[ni], 0,1,2,3,4,5,6,7);
                acc[mi][ni] = __builtin_amdgcn_mfma_scale_f32_16x16x128_f8f6f4(
                    af, bf, acc[mi][ni], 0, 0,
                    0, 0x7F7F7F7F, 0, 0x7F7F7F7F);   // unit scales
            }
        }
        __syncthreads();
    }

    // C/D layout: col = lane&15, row = quad*4 + reg
#pragma unroll
    for (int mi = 0; mi < 4; ++mi)
#pragma unroll
    for (int ni = 0; ni < 4; ++ni) {
        const int grow0 = m0 + wm + mi * 16 + quad * 4;
        const int gcol  = n0 + wn + ni * 16 + l15;
        if constexpr (EPI == 0) {
            if (gcol < HID) {
                const int b = grow0 >> 12, rloc = grow0 & (SEQ - 1);
                unsigned w = f2e4x4(silu_f(acc[mi][ni][0] * 0.0625f + f0[gcol]),
                                    silu_f(acc[mi][ni][1] * 0.0625f + f0[gcol]),
                                    silu_f(acc[mi][ni][2] * 0.0625f + f0[gcol]),
                                    silu_f(acc[mi][ni][3] * 0.0625f + f0[gcol]));
                *(unsigned*)(o0 + (size_t)b * HID * SEQ + (size_t)gcol * SEQ + rloc) = w;
            } else if (gcol < 2048) {
#pragma unroll
                for (int r = 0; r < 4; ++r)
                    gate[(size_t)(grow0 + r) * HID + (gcol - HID)] =
                        f2e4(silu_f(acc[mi][ni][r] * 0.0625f + f0[gcol]));
            } else {
                const int c = gcol - 2048;
#pragma unroll
                for (int r = 0; r < 4; ++r) {
                    float zf = silu_f(acc[mi][ni][r] * 0.0625f + f1[c]);
                    o1[(size_t)(grow0 + r) * QKD + c] = f2e4((zf * f2[c] + f4[c]) * 64.f);
                    o2[(size_t)(grow0 + r) * QKD + c] = f2e4((zf * f3[c] + f5[c]) * 64.f);
                }
            }
        } else if constexpr (EPI == 1) {
            unsigned char* Ao = o0 + (size_t)z * strOz;
#pragma unroll
            for (int r = 0; r < 4; ++r) {
                float t = fmaxf(acc[mi][ni][r], 0.f) * 0.0625f;
                Ao[(size_t)(grow0 + r) * SEQ + gcol] = f2e4(t * t);
            }
        } else if constexpr (EPI == 2) {
            unsigned char* gz = gate + (size_t)z * strOz;
            unsigned char* vo = o0 + (size_t)z * strOz;
#pragma unroll
            for (int r = 0; r < 4; ++r) {
                float g = e42f(gz[(size_t)(grow0 + r) * HID + gcol]);
                vo[(size_t)(grow0 + r) * HID + gcol] = f2e4(acc[mi][ni][r] * scale * g);
            }
        } else {
#pragma unroll
            for (int r = 0; r < 4; ++r)
                fo[(size_t)(grow0 + r) * DIM + gcol] =
                    acc[mi][ni][r] * scale + f0[gcol] + f1[(size_t)(grow0 + r) * DIM + gcol];
        }
    }
}

extern "C" void kernel_launch(void* const* d_in, const int* in_sizes, int n_in,
                              void* d_out, int out_size, void* d_ws, size_t ws_size,
                              hipStream_t stream) {
    const float* x     = (const float*)d_in[0];
    const float* nsc   = (const float*)d_in[1];
    const float* nbi   = (const float*)d_in[2];
    const float* Wh    = (const float*)d_in[3];
    const float* bh    = (const float*)d_in[4];
    const float* Wqk   = (const float*)d_in[5];
    const float* bqk   = (const float*)d_in[6];
    const float* gamma = (const float*)d_in[7];
    const float* beta  = (const float*)d_in[8];
    const float* Wout  = (const float*)d_in[9];
    const float* bout  = (const float*)d_in[10];
    float* out = (float*)d_out;

    uint8_t* ws = (uint8_t*)d_ws;
    size_t off = 0;
    auto alloc = [&](size_t n) { uint8_t* p = ws + off; off += (n + 255) & ~(size_t)255; return p; };
    unsigned char* normed8 = (unsigned char*)alloc((size_t)TOK * DIM);
    unsigned char* Wc8     = (unsigned char*)alloc((size_t)2176 * DIM);   // [WhT;WqkT] x16
    unsigned char* Wout8   = (unsigned char*)alloc((size_t)DIM * HID);    // x16
    unsigned char* vT8     = (unsigned char*)alloc((size_t)BAT * HID * SEQ);
    unsigned char* gbuf    = (unsigned char*)alloc((size_t)TOK * HID);    // gate fp8
    unsigned char* q8      = (unsigned char*)alloc((size_t)TOK * QKD);    // x64
    unsigned char* k8      = (unsigned char*)alloc((size_t)TOK * QKD);    // x64
    unsigned char* Ab8     = (unsigned char*)alloc((size_t)BAT * SEQ * SEQ); // x2^40
    unsigned char* vg8     = (unsigned char*)alloc((size_t)TOK * HID);    // x2^28

    if (ws_size < off) {
        copy_kernel<<<4096, 256, 0, stream>>>(x, out, TOK * DIM / 4);
        return;
    }

    ln_kernel<<<TOK / 4, 256, 0, stream>>>(x, nsc, nbi, normed8);
    tcast_f2e4_kernel<<<dim3(2048 / 32, DIM / 32), 256, 0, stream>>>(Wh, Wc8, DIM, 2048);
    tcast_f2e4_kernel<<<dim3(QKD / 32, DIM / 32), 256, 0, stream>>>(
        Wqk, Wc8 + (size_t)2048 * DIM, DIM, QKD);
    tcast_f2e4_kernel<<<dim3(DIM / 32, HID / 32), 256, 0, stream>>>(Wout, Wout8, HID, DIM);

    // hidden + qk fused: N = 2176, K = 512
    gemm8<0, 17><<<dim3(17, TOK / 128), 256, 0, stream>>>(
        normed8, Wc8, DIM, 0, 0, 0,
        bh, bqk, gamma, gamma + QKD, beta, beta + QKD,
        gbuf, vT8, q8, k8, nullptr, 0.f);

    // sim: K = 128 (single slab), z-batched
    gemm8<1, 32><<<dim3(SEQ / 128, SEQ / 128, BAT), 256, 0, stream>>>(
        q8, k8, QKD, (long)SEQ * QKD, (long)SEQ * QKD, (long)SEQ * SEQ,
        nullptr, nullptr, nullptr, nullptr, nullptr, nullptr,
        nullptr, Ab8, nullptr, nullptr, nullptr, 0.f);

    // A@v: K = 4096, z-batched; vg8 = acc * 2^-12 * gate
    gemm8<2, 8><<<dim3(HID / 128, SEQ / 128, BAT), 256, 0, stream>>>(
        Ab8, vT8, SEQ, (long)SEQ * SEQ, (long)HID * SEQ, (long)SEQ * HID,
        nullptr, nullptr, nullptr, nullptr, nullptr, nullptr,
        gbuf, vg8, nullptr, nullptr, nullptr, 0x1p-12f);

    // out: K = 1024; out = acc * 2^-32 + b_out + x
    gemm8<3, 4><<<dim3(DIM / 128, TOK / 128), 256, 0, stream>>>(
        vg8, Wout8, HID, 0, 0, 0,
        bout, x, nullptr, nullptr, nullptr, nullptr,
        nullptr, nullptr, nullptr, nullptr, out, 0x1p-32f);
}

// Round 7
// 284.670 us; speedup vs baseline: 1.2768x; 1.0670x over previous
//
#include <hip/hip_runtime.h>
#include <cstdint>
#include <cstddef>

#define DIM   512
#define QKD   128
#define HID   1024
#define SEQ   4096
#define BAT   4
#define TOK   (BAT*SEQ)

typedef float f32x4 __attribute__((ext_vector_type(4)));
typedef int   i32x4 __attribute__((ext_vector_type(4)));
typedef int   i32x8 __attribute__((ext_vector_type(8)));

__device__ __forceinline__ float silu_f(float x) { return x / (1.f + __expf(-x)); }

__device__ __forceinline__ unsigned char f2e4(float f) {
    int v = __builtin_amdgcn_cvt_pk_fp8_f32(f, 0.f, 0, false);
    return (unsigned char)(v & 0xff);
}
__device__ __forceinline__ unsigned f2e4x4(float a, float b, float c, float d) {
    int w = __builtin_amdgcn_cvt_pk_fp8_f32(a, b, 0, false);
    w = __builtin_amdgcn_cvt_pk_fp8_f32(c, d, w, true);
    return (unsigned)w;
}
__device__ __forceinline__ float e42f(unsigned char b) {
    return __builtin_amdgcn_cvt_f32_fp8((int)b, 0);
}

__device__ __forceinline__ void load16_lds(const void* gp, void* lp) {
    __builtin_amdgcn_global_load_lds(
        (const __attribute__((address_space(1))) unsigned int*)gp,
        (__attribute__((address_space(3))) unsigned int*)lp,
        16, 0, 0);
}

// ---------------- LayerNorm: fp32 x -> fp8 normed ----------------
__global__ __launch_bounds__(256) void ln_kernel(
    const float* __restrict__ x, const float* __restrict__ sc,
    const float* __restrict__ bi, unsigned char* __restrict__ out)
{
    const int lane = threadIdx.x & 63, wid = threadIdx.x >> 6;
    const int row  = blockIdx.x * 4 + wid;
    const float4* xr = (const float4*)(x + (size_t)row * DIM);
    float4 a = xr[lane], b = xr[64 + lane];
    float s = a.x + a.y + a.z + a.w + b.x + b.y + b.z + b.w;
    float q = a.x*a.x + a.y*a.y + a.z*a.z + a.w*a.w
            + b.x*b.x + b.y*b.y + b.z*b.z + b.w*b.w;
#pragma unroll
    for (int m = 1; m < 64; m <<= 1) { s += __shfl_xor(s, m); q += __shfl_xor(q, m); }
    const float mean = s * (1.f / DIM);
    const float var  = q * (1.f / DIM) - mean * mean;
    const float rs   = rsqrtf(var + 1e-5f);
    float4 s0 = ((const float4*)sc)[lane], s1 = ((const float4*)sc)[64 + lane];
    float4 b0 = ((const float4*)bi)[lane], b1 = ((const float4*)bi)[64 + lane];
    unsigned wlo = f2e4x4((a.x - mean) * rs * s0.x + b0.x,
                          (a.y - mean) * rs * s0.y + b0.y,
                          (a.z - mean) * rs * s0.z + b0.z,
                          (a.w - mean) * rs * s0.w + b0.w);
    unsigned whi = f2e4x4((b.x - mean) * rs * s1.x + b1.x,
                          (b.y - mean) * rs * s1.y + b1.y,
                          (b.z - mean) * rs * s1.z + b1.z,
                          (b.w - mean) * rs * s1.w + b1.w);
    unsigned char* orow = out + (size_t)row * DIM;
    *(unsigned*)(orow + 4 * lane)       = wlo;
    *(unsigned*)(orow + 256 + 4 * lane) = whi;
}

// ---------------- transpose-cast fp32 (RxC) -> fp8 (CxR), x16 ----------------
__global__ __launch_bounds__(256) void tcast_f2e4_kernel(
    const float* __restrict__ in, unsigned char* __restrict__ out, int R, int C)
{
    __shared__ float t[32][33];
    const int tx = threadIdx.x & 31, ty = threadIdx.x >> 5;
    const int c0 = blockIdx.x * 32, r0 = blockIdx.y * 32;
#pragma unroll
    for (int i = 0; i < 4; ++i)
        t[ty + i * 8][tx] = in[(size_t)(r0 + ty + i * 8) * C + c0 + tx];
    __syncthreads();
#pragma unroll
    for (int i = 0; i < 4; ++i)
        out[(size_t)(c0 + ty + i * 8) * R + r0 + tx] = f2e4(t[tx][ty + i * 8] * 16.f);
}

// ---------------- fallback: out = x ----------------
__global__ __launch_bounds__(256) void copy_kernel(
    const float* __restrict__ in, float* __restrict__ out, int n4)
{
    int i = blockIdx.x * 256 + threadIdx.x;
    int stride = gridDim.x * 256;
    for (; i < n4; i += stride)
        ((float4*)out)[i] = ((const float4*)in)[i];
}

// -------- MX-fp8 MFMA GEMM: C = A(MxK) * B(NxK)^T, 128x128 tile, BK=128 ------
// LDS bank-conflict fix (R7): 128-B row stride == 0 mod bank cycle, so the
// un-swizzled fragment read had all 16 l15-lanes on one 4-bank group (16-way).
// XOR-granule swizzle: stored position p of row r holds ORIGINAL granule
// p ^ (r&7); staging loads global granule sseg^(srow&7) into linear slot sseg,
// fragment reads granule (2q+h) from position (2q+h)^(l15&7) -> every bank
// group hit by exactly 2 lanes (free, m136).
// NX = gridDim.x for the XCD swizzle (R5: A@v FETCH 287->106 MB).
// EPI 0: hidden+qk fused (N=2176): v->vT fp8 T'posed | gate fp8 | q/k fp8 (x64)
// EPI 1: sim  — A8 = (relu(acc)/16)^2 = 2^40 relu(sim)^2 -> fp8
// EPI 2: av   — vg8 = acc * 2^-12 * gate -> fp8 (= 2^28 * V*gate)
// EPI 3: out  — fo = acc * 2^-32 + b_out + x  (fp32)
template<int EPI, int NX>
__global__ __launch_bounds__(256) void gemm8(
    const unsigned char* __restrict__ A, const unsigned char* __restrict__ B,
    int K, long strAz, long strBz, long strOz,
    const float* __restrict__ f0, const float* __restrict__ f1,
    const float* __restrict__ f2, const float* __restrict__ f3,
    const float* __restrict__ f4, const float* __restrict__ f5,
    unsigned char* __restrict__ gate,
    unsigned char* __restrict__ o0, unsigned char* __restrict__ o1,
    unsigned char* __restrict__ o2,
    float* __restrict__ fo, float scale)
{
    __shared__ unsigned char lds[32768];          // A: [0,16K), B: [16K,32K)
    const int tid = threadIdx.x;
    // XCD-locality swizzle (dispatch id -> tile coords)
    const int d  = blockIdx.x + NX * blockIdx.y;
    const int qd = d >> 3;
    const int m0 = ((d & 7) + 8 * (qd / NX)) * 128;
    const int n0 = (qd % NX) * 128;
    const int z  = blockIdx.z;
    A += (size_t)z * strAz;  B += (size_t)z * strBz;
    const int lane = tid & 63, wid = tid >> 6;
    const int wm   = (wid & 1) * 64, wn = (wid >> 1) * 64;
    const int l15  = lane & 15, quad = lane >> 4;

    f32x4 acc[4][4] = {};

    // staging: 128 rows x 128 B per matrix per iter; 4 issues of 32 rows each.
    // Bank swizzle: load global granule (sseg ^ (srow&7)) into LDS slot sseg.
    const int srow = tid >> 3, sseg = tid & 7;
    const int gseg = sseg ^ (srow & 7);
    const unsigned char* gA = A + (size_t)(m0 + srow) * K + gseg * 16;
    const unsigned char* gB = B + (size_t)(n0 + srow) * K + gseg * 16;
    unsigned char* lA = lds + (size_t)tid * 16;
    unsigned char* lB = lds + 16384 + (size_t)tid * 16;

    // fragment-read granule offsets (original granule 2q/2q+1 -> swizzled pos)
    const int olo = (((quad << 1) ^ (l15 & 7)) << 4);
    const int ohi = olo ^ 16;

    for (int kt = 0; kt < K; kt += 128) {
#pragma unroll
        for (int i = 0; i < 4; ++i)
            load16_lds(gA + (size_t)i * 32 * K + kt, lA + i * 4096);
#pragma unroll
        for (int i = 0; i < 4; ++i)
            load16_lds(gB + (size_t)i * 32 * K + kt, lB + i * 4096);
        __syncthreads();
        i32x4 alo[4], ahi[4], blo[4], bhi[4];
#pragma unroll
        for (int mi = 0; mi < 4; ++mi) {
            const unsigned char* p = lds + (wm + mi * 16 + l15) * 128;
            alo[mi] = *(const i32x4*)(p + olo); ahi[mi] = *(const i32x4*)(p + ohi);
        }
#pragma unroll
        for (int ni = 0; ni < 4; ++ni) {
            const unsigned char* p = lds + 16384 + (wn + ni * 16 + l15) * 128;
            blo[ni] = *(const i32x4*)(p + olo); bhi[ni] = *(const i32x4*)(p + ohi);
        }
#pragma unroll
        for (int mi = 0; mi < 4; ++mi) {
            i32x8 af = __builtin_shufflevector(alo[mi], ahi[mi], 0,1,2,3,4,5,6,7);
#pragma unroll
            for (int ni = 0; ni < 4; ++ni) {
                i32x8 bf = __builtin_shufflevector(blo[ni], bhi[ni], 0,1,2,3,4,5,6,7);
                acc[mi][ni] = __builtin_amdgcn_mfma_scale_f32_16x16x128_f8f6f4(
                    af, bf, acc[mi][ni], 0, 0,
                    0, 0x7F7F7F7F, 0, 0x7F7F7F7F);   // unit scales
            }
        }
        __syncthreads();
    }

    // C/D layout: col = lane&15, row = quad*4 + reg
#pragma unroll
    for (int mi = 0; mi < 4; ++mi)
#pragma unroll
    for (int ni = 0; ni < 4; ++ni) {
        const int grow0 = m0 + wm + mi * 16 + quad * 4;
        const int gcol  = n0 + wn + ni * 16 + l15;
        if constexpr (EPI == 0) {
            if (gcol < HID) {
                const int b = grow0 >> 12, rloc = grow0 & (SEQ - 1);
                unsigned w = f2e4x4(silu_f(acc[mi][ni][0] * 0.0625f + f0[gcol]),
                                    silu_f(acc[mi][ni][1] * 0.0625f + f0[gcol]),
                                    silu_f(acc[mi][ni][2] * 0.0625f + f0[gcol]),
                                    silu_f(acc[mi][ni][3] * 0.0625f + f0[gcol]));
                *(unsigned*)(o0 + (size_t)b * HID * SEQ + (size_t)gcol * SEQ + rloc) = w;
            } else if (gcol < 2048) {
#pragma unroll
                for (int r = 0; r < 4; ++r)
                    gate[(size_t)(grow0 + r) * HID + (gcol - HID)] =
                        f2e4(silu_f(acc[mi][ni][r] * 0.0625f + f0[gcol]));
            } else {
                const int c = gcol - 2048;
#pragma unroll
                for (int r = 0; r < 4; ++r) {
                    float zf = silu_f(acc[mi][ni][r] * 0.0625f + f1[c]);
                    o1[(size_t)(grow0 + r) * QKD + c] = f2e4((zf * f2[c] + f4[c]) * 64.f);
                    o2[(size_t)(grow0 + r) * QKD + c] = f2e4((zf * f3[c] + f5[c]) * 64.f);
                }
            }
        } else if constexpr (EPI == 1) {
            unsigned char* Ao = o0 + (size_t)z * strOz;
#pragma unroll
            for (int r = 0; r < 4; ++r) {
                float t = fmaxf(acc[mi][ni][r], 0.f) * 0.0625f;
                Ao[(size_t)(grow0 + r) * SEQ + gcol] = f2e4(t * t);
            }
        } else if constexpr (EPI == 2) {
            unsigned char* gz = gate + (size_t)z * strOz;
            unsigned char* vo = o0 + (size_t)z * strOz;
#pragma unroll
            for (int r = 0; r < 4; ++r) {
                float g = e42f(gz[(size_t)(grow0 + r) * HID + gcol]);
                vo[(size_t)(grow0 + r) * HID + gcol] = f2e4(acc[mi][ni][r] * scale * g);
            }
        } else {
#pragma unroll
            for (int r = 0; r < 4; ++r)
                fo[(size_t)(grow0 + r) * DIM + gcol] =
                    acc[mi][ni][r] * scale + f0[gcol] + f1[(size_t)(grow0 + r) * DIM + gcol];
        }
    }
}

extern "C" void kernel_launch(void* const* d_in, const int* in_sizes, int n_in,
                              void* d_out, int out_size, void* d_ws, size_t ws_size,
                              hipStream_t stream) {
    const float* x     = (const float*)d_in[0];
    const float* nsc   = (const float*)d_in[1];
    const float* nbi   = (const float*)d_in[2];
    const float* Wh    = (const float*)d_in[3];
    const float* bh    = (const float*)d_in[4];
    const float* Wqk   = (const float*)d_in[5];
    const float* bqk   = (const float*)d_in[6];
    const float* gamma = (const float*)d_in[7];
    const float* beta  = (const float*)d_in[8];
    const float* Wout  = (const float*)d_in[9];
    const float* bout  = (const float*)d_in[10];
    float* out = (float*)d_out;

    uint8_t* ws = (uint8_t*)d_ws;
    size_t off = 0;
    auto alloc = [&](size_t n) { uint8_t* p = ws + off; off += (n + 255) & ~(size_t)255; return p; };
    unsigned char* normed8 = (unsigned char*)alloc((size_t)TOK * DIM);
    unsigned char* Wc8     = (unsigned char*)alloc((size_t)2176 * DIM);   // [WhT;WqkT] x16
    unsigned char* Wout8   = (unsigned char*)alloc((size_t)DIM * HID);    // x16
    unsigned char* vT8     = (unsigned char*)alloc((size_t)BAT * HID * SEQ);
    unsigned char* gbuf    = (unsigned char*)alloc((size_t)TOK * HID);    // gate fp8
    unsigned char* q8      = (unsigned char*)alloc((size_t)TOK * QKD);    // x64
    unsigned char* k8      = (unsigned char*)alloc((size_t)TOK * QKD);    // x64
    unsigned char* Ab8     = (unsigned char*)alloc((size_t)BAT * SEQ * SEQ); // x2^40
    unsigned char* vg8     = (unsigned char*)alloc((size_t)TOK * HID);    // x2^28

    if (ws_size < off) {
        copy_kernel<<<4096, 256, 0, stream>>>(x, out, TOK * DIM / 4);
        return;
    }

    ln_kernel<<<TOK / 4, 256, 0, stream>>>(x, nsc, nbi, normed8);
    tcast_f2e4_kernel<<<dim3(2048 / 32, DIM / 32), 256, 0, stream>>>(Wh, Wc8, DIM, 2048);
    tcast_f2e4_kernel<<<dim3(QKD / 32, DIM / 32), 256, 0, stream>>>(
        Wqk, Wc8 + (size_t)2048 * DIM, DIM, QKD);
    tcast_f2e4_kernel<<<dim3(DIM / 32, HID / 32), 256, 0, stream>>>(Wout, Wout8, HID, DIM);

    // hidden + qk fused: N = 2176, K = 512
    gemm8<0, 17><<<dim3(17, TOK / 128), 256, 0, stream>>>(
        normed8, Wc8, DIM, 0, 0, 0,
        bh, bqk, gamma, gamma + QKD, beta, beta + QKD,
        gbuf, vT8, q8, k8, nullptr, 0.f);

    // sim: K = 128 (single slab), z-batched
    gemm8<1, 32><<<dim3(SEQ / 128, SEQ / 128, BAT), 256, 0, stream>>>(
        q8, k8, QKD, (long)SEQ * QKD, (long)SEQ * QKD, (long)SEQ * SEQ,
        nullptr, nullptr, nullptr, nullptr, nullptr, nullptr,
        nullptr, Ab8, nullptr, nullptr, nullptr, 0.f);

    // A@v: K = 4096, z-batched; vg8 = acc * 2^-12 * gate
    gemm8<2, 8><<<dim3(HID / 128, SEQ / 128, BAT), 256, 0, stream>>>(
        Ab8, vT8, SEQ, (long)SEQ * SEQ, (long)HID * SEQ, (long)SEQ * HID,
        nullptr, nullptr, nullptr, nullptr, nullptr, nullptr,
        gbuf, vg8, nullptr, nullptr, nullptr, 0x1p-12f);

    // out: K = 1024; out = acc * 2^-32 + b_out + x
    gemm8<3, 4><<<dim3(DIM / 128, TOK / 128), 256, 0, stream>>>(
        vg8, Wout8, HID, 0, 0, 0,
        bout, x, nullptr, nullptr, nullptr, nullptr,
        nullptr, nullptr, nullptr, nullptr, out, 0x1p-32f);
}